// Round 17
// baseline (496.831 us; speedup 1.0000x reference)
//
#include <hip/hip_runtime.h>
#include <hip/hip_bf16.h>

typedef __hip_bfloat16 bf16;
typedef __attribute__((ext_vector_type(8))) short  short8;   // 8 bf16, 4 VGPRs
typedef __attribute__((ext_vector_type(4))) short  short4v;  // 4 bf16, 2 VGPRs
typedef __attribute__((ext_vector_type(4))) float  f32x4;    // MFMA C/D

#define B_ 4
#define Q_ 600
#define L_ 2048
#define D_ 256
#define H_ 8
#define HD_ 32
#define DFF_ 2048
#define KD_ 32
#define SCALE_ 0.17677669529663687f           // 32^-0.5
#define L2E_   1.4426950408889634f
#define SL2E_  (SCALE_ * L2E_)

// ---- dtype-polymorphic access: MODE 0=bf16, 1=f32, 2=runtime(flag) --------
template<int MODE>
__device__ __forceinline__ float ldx(const void* p, size_t i, bool f32)
{
    if (MODE == 0) return __bfloat162float(((const bf16*)p)[i]);
    if (MODE == 1) return ((const float*)p)[i];
    return f32 ? ((const float*)p)[i] : __bfloat162float(((const bf16*)p)[i]);
}
__device__ __forceinline__ short8 ld8_f32(const float* p)
{
    const float4 a = *(const float4*)p;
    const float4 b = *(const float4*)(p + 4);
    union { short8 s; bf16 h[8]; } u;
    u.h[0] = __float2bfloat16(a.x); u.h[1] = __float2bfloat16(a.y);
    u.h[2] = __float2bfloat16(a.z); u.h[3] = __float2bfloat16(a.w);
    u.h[4] = __float2bfloat16(b.x); u.h[5] = __float2bfloat16(b.y);
    u.h[6] = __float2bfloat16(b.z); u.h[7] = __float2bfloat16(b.w);
    return u.s;
}
template<int MODE>
__device__ __forceinline__ short8 ld8x(const void* p, size_t i, bool f32)
{
    if (MODE == 0) return *(const short8*)((const bf16*)p + i);
    if (MODE == 1) return ld8_f32((const float*)p + i);
    return f32 ? ld8_f32((const float*)p + i) : *(const short8*)((const bf16*)p + i);
}

// ------------------------------------------------------------ dtype probe --
__global__ __launch_bounds__(256)
void detect_kernel(const unsigned short* __restrict__ q, int* __restrict__ flag)
{
    __shared__ float red[4];
    const int tid = threadIdx.x;
    unsigned short u = q[tid];
    float f = __uint_as_float(((unsigned)(u & 0x7FFF)) << 16);
    if (f != f) f = 1e30f;
    #pragma unroll
    for (int o = 32; o > 0; o >>= 1) f = fmaxf(f, __shfl_xor(f, o));
    if ((tid & 63) == 0) red[tid >> 6] = f;
    __syncthreads();
    if (tid == 0) {
        float m = fmaxf(fmaxf(red[0], red[1]), fmaxf(red[2], red[3]));
        *flag = (m > 100.f) ? 1 : 0;
    }
}

// ------------------------------------------------------- GEMM core (64x64) -
template<int AM>
__device__ __forceinline__ void gemm_core(const void* __restrict__ A,
    const void* __restrict__ W, int M, int K, int kbeg, int kend,
    int bm, int bn, bool f32, bf16* As, bf16* Bs, f32x4 (&acc)[2][2])
{
    const int tid = threadIdx.x;
    const int w = tid >> 6, lane = tid & 63;
    const int quad = lane >> 4, l16 = lane & 15;
    const int wm = (w & 1) << 5, wn = (w >> 1) << 5;
    const int srow = tid >> 2, scol = (tid & 3) << 3;
    const int gma = (bm + srow < M) ? bm + srow : M - 1;

    short8 pa = ld8x<AM>(A, (size_t)gma * K + kbeg + scol, f32);
    short8 pb = ld8x<2>(W, (size_t)(bn + srow) * K + kbeg + scol, f32);

    for (int k0 = kbeg; k0 < kend; k0 += 32) {
        *(short8*)&As[srow * 40 + scol] = pa;
        *(short8*)&Bs[srow * 40 + scol] = pb;
        __syncthreads();
        if (k0 + 32 < kend) {
            pa = ld8x<AM>(A, (size_t)gma * K + k0 + 32 + scol, f32);
            pb = ld8x<2>(W, (size_t)(bn + srow) * K + k0 + 32 + scol, f32);
        }
        short8 af[2], bfr[2];
        #pragma unroll
        for (int t = 0; t < 2; t++) {
            af[t]  = *(const short8*)&As[(wm + t * 16 + l16) * 40 + quad * 8];
            bfr[t] = *(const short8*)&Bs[(wn + t * 16 + l16) * 40 + quad * 8];
        }
        #pragma unroll
        for (int mt = 0; mt < 2; mt++)
            #pragma unroll
            for (int nt = 0; nt < 2; nt++)
                acc[mt][nt] = __builtin_amdgcn_mfma_f32_16x16x32_bf16(
                    af[mt], bfr[nt], acc[mt][nt], 0, 0, 0);
        __syncthreads();
    }
}

// full-K 64x64 gemm with bias epilogue -> bf16 (A/W/bias runtime dtype)
__device__ __forceinline__ void gemm64_bf16out(const void* A, const void* W,
    const void* bs, bf16* C, int M, int N, int K, int bm, int bn, bool f32,
    bf16* As, bf16* Bs)
{
    f32x4 acc[2][2] = {{{0.f,0.f,0.f,0.f},{0.f,0.f,0.f,0.f}},
                       {{0.f,0.f,0.f,0.f},{0.f,0.f,0.f,0.f}}};
    gemm_core<2>(A, W, M, K, 0, K, bm, bn, f32, As, Bs, acc);
    const int tid = threadIdx.x;
    const int w = tid >> 6, lane = tid & 63;
    const int quad = lane >> 4, l16 = lane & 15;
    const int wm = (w & 1) << 5, wn = (w >> 1) << 5;
    #pragma unroll
    for (int mt = 0; mt < 2; mt++)
        #pragma unroll
        for (int r = 0; r < 4; r++) {
            const int row = bm + wm + mt * 16 + quad * 4 + r;
            if (row >= M) continue;
            #pragma unroll
            for (int nt = 0; nt < 2; nt++) {
                const int col = bn + wn + nt * 16 + l16;
                C[(size_t)row * N + col] =
                    __float2bfloat16(acc[mt][nt][r] + ldx<2>(bs, col, f32));
            }
        }
}

// -------------------------------------- fused input stage (L1 + KV + bias) -
// blocks [0,456): QKV proj (12x38) | [456,1480): K/V proj (8x128) |
// [1480,3880): bias_pre. All depend only on inputs+flag.
__global__ __launch_bounds__(256)
void input_stage(const void* __restrict__ queries, const void* __restrict__ sa_in_w,
                 const void* __restrict__ sa_in_b, bf16* __restrict__ qkv,
                 const void* __restrict__ memory,
                 const void* __restrict__ kw, const void* __restrict__ kb,
                 const void* __restrict__ vw, const void* __restrict__ vb,
                 bf16* __restrict__ kf, bf16* __restrict__ vf,
                 const void* __restrict__ qp, const void* __restrict__ mp,
                 const void* __restrict__ w1, const void* __restrict__ b1,
                 const void* __restrict__ w2, const void* __restrict__ b2,
                 const void* __restrict__ betap, bf16* __restrict__ biasT,
                 const int* __restrict__ flagp)
{
    const bool f32 = (*flagp != 0);
    __shared__ alignas(16) bf16 sAB[2 * 64 * 40];
    const int id = blockIdx.x;
    if (id < 456) {
        gemm64_bf16out(queries, sa_in_w, sa_in_b, qkv, 2400, 768, 256,
                       (id / 12) << 6, (id % 12) << 6, f32, sAB, sAB + 64 * 40);
    } else if (id < 1480) {
        const int t = id - 456;
        const int bx = t & 7, sel = bx >> 2;
        gemm64_bf16out(memory, sel ? vw : kw, sel ? vb : kb, sel ? vf : kf,
                       8192, 256, 256, (t >> 3) << 6, (bx & 3) << 6, f32,
                       sAB, sAB + 64 * 40);
    } else {
        float* fs = (float*)sAB;
        float *sw1 = fs, *sb1 = fs + 32, *sw2 = fs + 64, *scst = fs + 96;
        const int tid = threadIdx.x;
        if (tid < KD_) {
            sw1[tid] = ldx<2>(w1, tid, f32);
            sb1[tid] = ldx<2>(b1, tid, f32);
            sw2[tid] = ldx<2>(w2, tid, f32);
        }
        if (tid == 0) { scst[0] = ldx<2>(b2, 0, f32); scst[1] = L2E_ * ldx<2>(betap, 0, f32); }
        __syncthreads();
        const int idx = (id - 1480) * 256 + tid;     // 614400 = B*L*75
        const int q8 = idx % 75;
        const int t2 = idx / 75;
        const int l = t2 % L_, b = t2 / L_;
        const int q0 = q8 * 8;
        const float mx = ldx<2>(mp, (size_t)(b * L_ + l) * 3 + 0, f32);
        const float my = ldx<2>(mp, (size_t)(b * L_ + l) * 3 + 1, f32);
        const float mz = ldx<2>(mp, (size_t)(b * L_ + l) * 3 + 2, f32);
        union { short8 s; bf16 h[8]; } res;
        #pragma unroll
        for (int j = 0; j < 8; j++) {
            const int q = q0 + j;
            float dx = ldx<2>(qp, (size_t)(b * Q_ + q) * 3 + 0, f32) - mx;
            float dy = ldx<2>(qp, (size_t)(b * Q_ + q) * 3 + 1, f32) - my;
            float dz = ldx<2>(qp, (size_t)(b * Q_ + q) * 3 + 2, f32) - mz;
            float dist = sqrtf(dx * dx + dy * dy + dz * dz);
            float acc = scst[0];
            #pragma unroll
            for (int k = 0; k < KD_; k++)
                acc += fmaxf(dist * sw1[k] + sb1[k], 0.f) * sw2[k];
            acc = fminf(fmaxf(acc, -10.f), 0.f);
            res.h[j] = __float2bfloat16(scst[1] * acc);
        }
        *(short8*)(biasT + ((size_t)(b * L_) + l) * Q_ + q0) = res.s;
    }
}

// ----------------------------------------------------------- MFMA GEMM -----
template<int AM, int RM, int CM, bool RELU, int SPLIT>
__global__ __launch_bounds__(256)
void gemm_mfma(const void* __restrict__ A, const void* __restrict__ W,
               const void* __restrict__ bias, const void* __restrict__ R,
               void* __restrict__ C, int M, int N, int K,
               const int* __restrict__ flagp)
{
    const bool f32 = (*flagp != 0);
    __shared__ alignas(16) bf16 As[64 * 40];
    __shared__ alignas(16) bf16 Bs[64 * 40];
    const int bm = blockIdx.y << 6, bn = blockIdx.x << 6;
    const int KS = K / SPLIT, z = (SPLIT > 1) ? blockIdx.z : 0;

    f32x4 acc[2][2] = {{{0.f,0.f,0.f,0.f},{0.f,0.f,0.f,0.f}},
                       {{0.f,0.f,0.f,0.f},{0.f,0.f,0.f,0.f}}};
    gemm_core<AM>(A, W, M, K, z * KS, z * KS + KS, bm, bn, f32, As, Bs, acc);

    const int tid = threadIdx.x;
    const int w = tid >> 6, lane = tid & 63;
    const int quad = lane >> 4, l16 = lane & 15;
    const int wm = (w & 1) << 5, wn = (w >> 1) << 5;

    #pragma unroll
    for (int mt = 0; mt < 2; mt++) {
        #pragma unroll
        for (int r = 0; r < 4; r++) {
            const int row = bm + wm + mt * 16 + quad * 4 + r;
            if (row >= M) continue;
            #pragma unroll
            for (int nt = 0; nt < 2; nt++) {
                const int col = bn + wn + nt * 16 + l16;
                if (SPLIT > 1) {
                    ((float*)C)[((size_t)z * M + row) * N + col] = acc[mt][nt][r];
                } else {
                    float v = acc[mt][nt][r] + ldx<2>(bias, col, f32);
                    if (RM >= 0) v += ldx<RM < 0 ? 0 : RM>(R, (size_t)row * N + col, f32);
                    if (RELU) v = fmaxf(v, 0.f);
                    if (CM == 0) ((bf16*)C)[(size_t)row * N + col] = __float2bfloat16(v);
                    else         ((float*)C)[(size_t)row * N + col] = v;
                }
            }
        }
    }
}

// -------------------------------------------- split-K reduce + res + LN ----
template<int RM, int OM, int S>
__global__ __launch_bounds__(64)
void red_ln(const float* __restrict__ P, const void* __restrict__ bias,
            const void* __restrict__ R, const void* __restrict__ gg,
            const void* __restrict__ bb, void* __restrict__ Y,
            int M, const int* __restrict__ flagp)
{
    const bool f32 = (*flagp != 0);
    const int row = blockIdx.x, lane = threadIdx.x;
    const int d0 = lane * 4;
    float v[4];
    {
        float4 a = *(const float4*)(P + ((size_t)0 * M + row) * D_ + d0);
        v[0] = a.x; v[1] = a.y; v[2] = a.z; v[3] = a.w;
    }
    #pragma unroll
    for (int s = 1; s < S; s++) {
        float4 a = *(const float4*)(P + ((size_t)s * M + row) * D_ + d0);
        v[0] += a.x; v[1] += a.y; v[2] += a.z; v[3] += a.w;
    }
    #pragma unroll
    for (int j = 0; j < 4; j++)
        v[j] += ldx<2>(bias, d0 + j, f32) + ldx<RM>(R, (size_t)row * D_ + d0 + j, f32);

    float s1 = v[0] + v[1] + v[2] + v[3];
    float s2 = v[0]*v[0] + v[1]*v[1] + v[2]*v[2] + v[3]*v[3];
    #pragma unroll
    for (int o = 32; o > 0; o >>= 1) {
        s1 += __shfl_xor(s1, o);
        s2 += __shfl_xor(s2, o);
    }
    const float mean = s1 * (1.f / D_);
    const float var = s2 * (1.f / D_) - mean * mean;
    const float rinv = rsqrtf(var + 1e-5f);
    float o[4];
    #pragma unroll
    for (int j = 0; j < 4; j++)
        o[j] = (v[j] - mean) * rinv * ldx<2>(gg, d0 + j, f32) + ldx<2>(bb, d0 + j, f32);
    const size_t i = (size_t)row * D_ + d0;
    if (OM == 1 || (OM == 2 && f32)) {
        float4 t{o[0], o[1], o[2], o[3]};
        *(float4*)((float*)Y + i) = t;
    } else {
        bf16* y = (bf16*)Y + i;
        y[0] = __float2bfloat16(o[0]); y[1] = __float2bfloat16(o[1]);
        y[2] = __float2bfloat16(o[2]); y[3] = __float2bfloat16(o[3]);
    }
}

// ------------------------------------------------------- flash attention ---
// 1-D grid, XCD-grouped. Bias pre-transposed [b][l][q], L2E*beta folded.
// Static-max softmax (scores provably bounded). Row-sum via ones-row Vt.
// Register-prefetch double-buffer. Psh is wave-private (rows w*16..w*16+15):
// no barrier between exp-write and PV-read (proven rounds 9-11).
template<bool HASBIAS, int NSEG>
__global__ __launch_bounds__(256)
void flash_attn(const bf16* __restrict__ Qm, int qs,
                const bf16* __restrict__ Km, int ks,
                const bf16* __restrict__ Vm, int vs,
                const bf16* __restrict__ biasT,       // [b][l][q], pre-scaled
                bf16* __restrict__ pO, float* __restrict__ pml,
                int NQ, int LK)
{
    __shared__ alignas(16) bf16 Ksh[64 * 40];
    __shared__ alignas(16) bf16 Vt[48 * 72];
    __shared__ alignas(16) bf16 Psh[64 * 72];
    __shared__ alignas(16) bf16 Bsh[HASBIAS ? 64 * 72 : 8];

    const int tid = threadIdx.x;
    const int w = tid >> 6, lane = tid & 63;
    const int quad = lane >> 4, l16 = lane & 15;

    const int id = blockIdx.x;
    const int g  = ((id >> 6) << 3) + (id & 7);
    const int h  = (id >> 3) & 7;
    const int qt = g % 10;
    const int zz = g / 10;
    const int b = zz & 3, seg = zz >> 2;
    const int q0 = qt * 64;
    const int segLen = LK / NSEG;
    const int lbeg = seg * segLen, lend = lbeg + segLen;

    // ones/zero rows of Vt (rows 32..47), written once
    for (int i = tid; i < 16 * 72; i += 256) {
        int rr = 32 + i / 72, cc = i % 72;
        Vt[rr * 72 + cc] = __float2bfloat16(rr == 32 ? 1.f : 0.f);
    }

    int qrow = q0 + w * 16 + l16; if (qrow > NQ - 1) qrow = NQ - 1;
    const short8 aq = *(const short8*)(Qm + (size_t)(b * NQ + qrow) * qs + h * HD_ + quad * 8);

    f32x4 O0 = {0.f,0.f,0.f,0.f}, O1 = {0.f,0.f,0.f,0.f}, O2 = {0.f,0.f,0.f,0.f};

    const int srow = tid >> 2, sc4 = tid & 3;
    const int nch = (segLen + 63) >> 6;

    short8 k8, v8, bb8[2];
    auto load_chunk = [&](int l0c) {
        int lg = l0c + srow; if (lg > LK - 1) lg = LK - 1;
        k8 = *(const short8*)(Km + (size_t)(b * LK + lg) * ks + h * HD_ + sc4 * 8);
        v8 = *(const short8*)(Vm + (size_t)(b * LK + lg) * vs + h * HD_ + sc4 * 8);
        if (HASBIAS) {
            #pragma unroll
            for (int rep = 0; rep < 2; rep++) {
                int chid = tid + rep * 256;
                int ll = chid >> 3, qc = chid & 7;
                int qread = q0 + qc * 8;
                if (qread > NQ - 8) qread = NQ - 8;   // clamp; dead cols only
                bb8[rep] = *(const short8*)(biasT + ((size_t)(b * LK) + l0c + ll) * Q_ + qread);
            }
        }
    };
    load_chunk(lbeg);

    for (int ch = 0; ch < nch; ch++) {
        const int l0 = lbeg + (ch << 6);
        // write staged registers -> LDS
        *(short8*)&Ksh[srow * 40 + sc4 * 8] = k8;
        {
            const int swc = srow ^ (sc4 * 16);
            #pragma unroll
            for (int j = 0; j < 8; j++)
                Vt[(sc4 * 8 + j) * 72 + swc] = ((const bf16*)&v8)[j];
        }
        if (HASBIAS) {
            #pragma unroll
            for (int rep = 0; rep < 2; rep++) {
                int chid = tid + rep * 256;
                int ll = chid >> 3, qc = chid & 7;
                *(short8*)&Bsh[ll * 72 + qc * 8] = bb8[rep];
            }
        }
        __syncthreads();
        if (ch + 1 < nch) load_chunk(l0 + 64);   // prefetch next chunk

        f32x4 sv[4];
        #pragma unroll
        for (int jt = 0; jt < 4; jt++) {
            short8 kb = *(const short8*)&Ksh[(jt * 16 + l16) * 40 + quad * 8];
            sv[jt] = __builtin_amdgcn_mfma_f32_16x16x32_bf16(aq, kb, (f32x4){0.f,0.f,0.f,0.f}, 0, 0, 0);
        }
        // static-max softmax: P = exp2(t) directly
        if (l0 + 64 <= lend) {                 // full chunk (always, for cross)
            #pragma unroll
            for (int jt = 0; jt < 4; jt++) {
                if (HASBIAS) {
                    short4v bb = *(const short4v*)&Bsh[(jt * 16 + l16) * 72 + w * 16 + quad * 4];
                    #pragma unroll
                    for (int r = 0; r < 4; r++)
                        Psh[(w * 16 + quad * 4 + r) * 72 + jt * 16 + l16] =
                            __float2bfloat16(exp2f(sv[jt][r] * SL2E_ +
                                __bfloat162float(((const bf16*)&bb)[r])));
                } else {
                    #pragma unroll
                    for (int r = 0; r < 4; r++)
                        Psh[(w * 16 + quad * 4 + r) * 72 + jt * 16 + l16] =
                            __float2bfloat16(exp2f(sv[jt][r] * SL2E_));
                }
            }
        } else {                                // partial tail (self only)
            #pragma unroll
            for (int jt = 0; jt < 4; jt++) {
                const bool valid = (l0 + jt * 16 + l16) < lend;
                #pragma unroll
                for (int r = 0; r < 4; r++)
                    Psh[(w * 16 + quad * 4 + r) * 72 + jt * 16 + l16] =
                        __float2bfloat16(valid ? exp2f(sv[jt][r] * SL2E_) : 0.f);
            }
        }
        // Psh rows are wave-private: no barrier needed before PV reads
        const int sw0 = 16 * (l16 >> 3);
        const int sw1 = 16 * (2 + (l16 >> 3));
        #pragma unroll
        for (int kt = 0; kt < 2; kt++) {
            short8 ap  = *(const short8*)&Psh[(w * 16 + l16) * 72 + kt * 32 + quad * 8];
            short8 bv0 = *(const short8*)&Vt[(l16) * 72 + ((kt * 32 + quad * 8) ^ sw0)];
            short8 bv1 = *(const short8*)&Vt[(16 + l16) * 72 + ((kt * 32 + quad * 8) ^ sw1)];
            short8 bon = *(const short8*)&Vt[(32 + l16) * 72 + kt * 32 + quad * 8];
            O0 = __builtin_amdgcn_mfma_f32_16x16x32_bf16(ap, bv0, O0, 0, 0, 0);
            O1 = __builtin_amdgcn_mfma_f32_16x16x32_bf16(ap, bv1, O1, 0, 0, 0);
            O2 = __builtin_amdgcn_mfma_f32_16x16x32_bf16(ap, bon, O2, 0, 0, 0);
        }
        __syncthreads();
    }

    #pragma unroll
    for (int r = 0; r < 4; r++) {
        const int qg = q0 + w * 16 + quad * 4 + r;
        if (qg >= NQ) continue;
        const float li = __shfl(O2[r], lane & 48);   // col-0 lane of this quad
        const float inv = 1.f / li;
        const size_t rowp = (size_t)(((seg * 4 + b) * 8) + h) * NQ + qg;
        bf16* op = pO + rowp * 32;
        op[l16]      = __float2bfloat16(O0[r] * inv);
        op[16 + l16] = __float2bfloat16(O1[r] * inv);
        if (l16 == 0) { pml[rowp * 2 + 0] = 0.f; pml[rowp * 2 + 1] = O2[r]; }
    }
}

// combine NSEG partials: out = sum_s w_s * Ohat_s, w_s = l_s*2^(m_s-M)/W
template<int NSEG>
__global__ __launch_bounds__(256)
void attn_combine(const bf16* __restrict__ pO, const float* __restrict__ pml,
                  bf16* __restrict__ ctx, int NQ)
{
    const int t = blockIdx.x * 256 + threadIdx.x;
    const int row = t >> 5, d = t & 31;
    const int stride = 32 * NQ;
    float ms[NSEG], ls[NSEG];
    float M = -3e38f;
    #pragma unroll
    for (int s = 0; s < NSEG; s++) {
        ms[s] = pml[(size_t)(s * stride + row) * 2 + 0];
        ls[s] = pml[(size_t)(s * stride + row) * 2 + 1];
        M = fmaxf(M, ms[s]);
    }
    float W = 0.f, acc = 0.f;
    #pragma unroll
    for (int s = 0; s < NSEG; s++) {
        float wgt = ls[s] * exp2f(ms[s] - M);
        W += wgt;
        acc += wgt * __bfloat162float(pO[(size_t)(s * stride + row) * 32 + d]);
    }
    const int bh = row / NQ, q = row - bh * NQ;
    ctx[((size_t)((bh >> 3) * NQ + q)) * D_ + (bh & 7) * HD_ + d] = __float2bfloat16(acc / W);
}

// ---------------------------------------------------------------- launch ---
extern "C" void kernel_launch(void* const* d_in, const int* in_sizes, int n_in,
                              void* d_out, int out_size, void* d_ws, size_t ws_size,
                              hipStream_t stream)
{
    const void* queries   = d_in[0];
    const void* memory    = d_in[1];
    const void* memory_pos= d_in[2];
    const void* query_pos = d_in[3];
    const void* sa_in_w   = d_in[4];
    const void* sa_in_b   = d_in[5];
    const void* sa_out_w  = d_in[6];
    const void* sa_out_b  = d_in[7];
    const void* norm1_g   = d_in[8];
    const void* norm1_b   = d_in[9];
    const void* q_w  = d_in[10], *q_b  = d_in[11];
    const void* k_w  = d_in[12], *k_b  = d_in[13];
    const void* v_w  = d_in[14], *v_b  = d_in[15];
    const void* o_w  = d_in[16], *o_b  = d_in[17];
    const void* norm2_g = d_in[18], *norm2_b = d_in[19];
    const void* beta  = d_in[20];
    const void* dk_w1 = d_in[21], *dk_b1 = d_in[22];
    const void* dk_w2 = d_in[23], *dk_b2 = d_in[24];
    const void* ffn_w1 = d_in[25], *ffn_b1 = d_in[26];
    const void* ffn_w2 = d_in[27], *ffn_b2 = d_in[28];
    const void* norm3_g = d_in[29], *norm3_b = d_in[30];

    // ---- workspace layout for the FUSED schedule, total 30,507,012 B ----
    // kf/vf/biasT live input_stage..L9 and are overlaid by NOTHING until L9.
    char* base = (char*)d_ws;
    bf16*  kf     = (bf16*)(base + 0);           // 8192x256 bf16 [in..L9]
    bf16*  vf     = (bf16*)(base + 4194304);     // 8192x256 bf16 [in..L9]
    bf16*  biasT  = (bf16*)(base + 8388608);     // [b][l][q] bf16 [in..L9]
    bf16*  qkv    = (bf16*)(base + 18219008);    // 2400x768 bf16 [in..L2]
    bf16*  sactx  = (bf16*)(base + 18219008);    // 2400x256 bf16 [combS..L3]  (over dead qkv)
    bf16*  selfO  = (bf16*)(base + 21905408);    // 2x19200x32 bf16 [L2..combS]
    float* selfML = (float*)(base + 24363008);   // 2x19200x2 f32  [L2..combS]
    float* P3     = (float*)(base + 21905408);   // 2x2400x256 f32 [L3..R1]    (over dead selfO/ML)
    float* x1     = (float*)(base + 26820608);   // 2400x256 f32   [R1..R2]
    bf16*  qproj  = (bf16*)(base + 29278208);    // 2400x256 bf16  [L5..L9]
    bf16*  crossO = (bf16*)(base + 21905408);    // 4x19200x32 bf16 [L9..combC] (over dead P3)
    float* crossML= (float*)(base + 19447808);   // 4x19200x2 f32  [L9..combC] (over dead qkv)
    bf16*  cactx  = (bf16*)(base + 18219008);    // 2400x256 bf16  [combC..L10] (over dead sactx)
    float* P10    = (float*)(base + 0);          // 2x2400x256 f32 [L10..R2]   (over dead kf)
    float* x2     = (float*)(base + 4915200);    // 2400x256 f32   [R2..R3]    (over dead vf)
    bf16*  ffnh   = (bf16*)(base + 8388608);     // 2400x2048 bf16 [L12..L13]  (over dead biasT)
    float* P13    = (float*)(base + 18219008);   // 4x2400x256 f32 [L13..R3]   (over dead mid)
    int*   flag   = (int*)(base + 30507008);

    const dim3 blk(256);

    detect_kernel<<<1, 256, 0, stream>>>((const unsigned short*)queries, flag);
    // INPUT. fused: QKV proj + K/V proj + geometric bias  (3880 blocks)
    input_stage<<<3880, blk, 0, stream>>>(
        queries, sa_in_w, sa_in_b, qkv,
        memory, k_w, k_b, v_w, v_b, kf, vf,
        query_pos, memory_pos, dk_w1, dk_b1, dk_w2, dk_b2, beta, biasT, flag);
    // L2. self-attention (1-D XCD-grouped grid, L-split x2) + combine
    flash_attn<false, 2><<<640, blk, 0, stream>>>(
        qkv, 768, qkv + 256, 768, qkv + 512, 768, nullptr,
        selfO, selfML, 600, 600);
    attn_combine<2><<<2400, blk, 0, stream>>>(selfO, selfML, sactx, 600);
    // L3. out-proj, split-K x2 -> P3
    gemm_mfma<0, -1, 1, false, 2><<<dim3(4, 38, 2), blk, 0, stream>>>(
        sactx, sa_out_w, nullptr, nullptr, P3, 2400, 256, 256, flag);
    // R1. reduce + bias + residual(queries) + LN1 -> x1
    red_ln<2, 1, 2><<<2400, 64, 0, stream>>>(
        P3, sa_out_b, queries, norm1_g, norm1_b, x1, 2400, flag);
    // L5. cross Q projection
    gemm_mfma<1, -1, 0, false, 1><<<dim3(4, 38), blk, 0, stream>>>(
        x1, q_w, q_b, nullptr, qproj, 2400, 256, 256, flag);
    // L9. cross-attention (1-D XCD-grouped grid, L-split x4) + combine
    flash_attn<true, 4><<<1280, blk, 0, stream>>>(
        qproj, 256, kf, 256, vf, 256, biasT,
        crossO, crossML, 600, 2048);
    attn_combine<4><<<2400, blk, 0, stream>>>(crossO, crossML, cactx, 600);
    // L10. o-proj, split-K x2 -> P10
    gemm_mfma<0, -1, 1, false, 2><<<dim3(4, 38, 2), blk, 0, stream>>>(
        cactx, o_w, nullptr, nullptr, P10, 2400, 256, 256, flag);
    // R2. reduce + bias + residual(x1) + LN2 -> x2
    red_ln<1, 1, 2><<<2400, 64, 0, stream>>>(
        P10, o_b, x1, norm2_g, norm2_b, x2, 2400, flag);
    // L12. FFN up + ReLU
    gemm_mfma<1, -1, 0, true, 1><<<dim3(32, 38), blk, 0, stream>>>(
        x2, ffn_w1, ffn_b1, nullptr, ffnh, 2400, 2048, 256, flag);
    // L13. FFN down, split-K x4 -> P13
    gemm_mfma<0, -1, 1, false, 4><<<dim3(4, 38, 4), blk, 0, stream>>>(
        ffnh, ffn_w2, nullptr, nullptr, P13, 2400, 256, 2048, flag);
    // R3. reduce + bias + residual(x2) + LN3 -> d_out
    red_ln<1, 2, 4><<<2400, 64, 0, stream>>>(
        P13, ffn_b2, x2, norm3_g, norm3_b, d_out, 2400, flag);
}

// Round 18
// 296.080 us; speedup vs baseline: 1.6780x; 1.6780x over previous
//
#include <hip/hip_runtime.h>
#include <hip/hip_bf16.h>

typedef __hip_bfloat16 bf16;
typedef __attribute__((ext_vector_type(8))) short  short8;   // 8 bf16, 4 VGPRs
typedef __attribute__((ext_vector_type(4))) short  short4v;  // 4 bf16, 2 VGPRs
typedef __attribute__((ext_vector_type(4))) float  f32x4;    // MFMA C/D

#define B_ 4
#define Q_ 600
#define L_ 2048
#define D_ 256
#define H_ 8
#define HD_ 32
#define DFF_ 2048
#define KD_ 32
#define SCALE_ 0.17677669529663687f           // 32^-0.5
#define L2E_   1.4426950408889634f
#define SL2E_  (SCALE_ * L2E_)

// ---- dtype-polymorphic access: MODE 0=bf16, 1=f32, 2=runtime(flag) --------
template<int MODE>
__device__ __forceinline__ float ldx(const void* p, size_t i, bool f32)
{
    if (MODE == 0) return __bfloat162float(((const bf16*)p)[i]);
    if (MODE == 1) return ((const float*)p)[i];
    return f32 ? ((const float*)p)[i] : __bfloat162float(((const bf16*)p)[i]);
}
__device__ __forceinline__ short8 ld8_f32(const float* p)
{
    const float4 a = *(const float4*)p;
    const float4 b = *(const float4*)(p + 4);
    union { short8 s; bf16 h[8]; } u;
    u.h[0] = __float2bfloat16(a.x); u.h[1] = __float2bfloat16(a.y);
    u.h[2] = __float2bfloat16(a.z); u.h[3] = __float2bfloat16(a.w);
    u.h[4] = __float2bfloat16(b.x); u.h[5] = __float2bfloat16(b.y);
    u.h[6] = __float2bfloat16(b.z); u.h[7] = __float2bfloat16(b.w);
    return u.s;
}
template<int MODE>
__device__ __forceinline__ short8 ld8x(const void* p, size_t i, bool f32)
{
    if (MODE == 0) return *(const short8*)((const bf16*)p + i);
    if (MODE == 1) return ld8_f32((const float*)p + i);
    return f32 ? ld8_f32((const float*)p + i) : *(const short8*)((const bf16*)p + i);
}

// ------------------------------------------------------------ dtype probe --
__global__ __launch_bounds__(256)
void detect_kernel(const unsigned short* __restrict__ q, int* __restrict__ flag)
{
    __shared__ float red[4];
    const int tid = threadIdx.x;
    unsigned short u = q[tid];
    float f = __uint_as_float(((unsigned)(u & 0x7FFF)) << 16);
    if (f != f) f = 1e30f;
    #pragma unroll
    for (int o = 32; o > 0; o >>= 1) f = fmaxf(f, __shfl_xor(f, o));
    if ((tid & 63) == 0) red[tid >> 6] = f;
    __syncthreads();
    if (tid == 0) {
        float m = fmaxf(fmaxf(red[0], red[1]), fmaxf(red[2], red[3]));
        *flag = (m > 100.f) ? 1 : 0;
    }
}

// ------------------------------------------------------- GEMM core (64x64) -
template<int AM>
__device__ __forceinline__ void gemm_core(const void* __restrict__ A,
    const void* __restrict__ W, int M, int K, int kbeg, int kend,
    int bm, int bn, bool f32, bf16* As, bf16* Bs, f32x4 (&acc)[2][2])
{
    const int tid = threadIdx.x;
    const int w = tid >> 6, lane = tid & 63;
    const int quad = lane >> 4, l16 = lane & 15;
    const int wm = (w & 1) << 5, wn = (w >> 1) << 5;
    const int srow = tid >> 2, scol = (tid & 3) << 3;
    const int gma = (bm + srow < M) ? bm + srow : M - 1;

    short8 pa = ld8x<AM>(A, (size_t)gma * K + kbeg + scol, f32);
    short8 pb = ld8x<2>(W, (size_t)(bn + srow) * K + kbeg + scol, f32);

    for (int k0 = kbeg; k0 < kend; k0 += 32) {
        *(short8*)&As[srow * 40 + scol] = pa;
        *(short8*)&Bs[srow * 40 + scol] = pb;
        __syncthreads();
        if (k0 + 32 < kend) {
            pa = ld8x<AM>(A, (size_t)gma * K + k0 + 32 + scol, f32);
            pb = ld8x<2>(W, (size_t)(bn + srow) * K + k0 + 32 + scol, f32);
        }
        short8 af[2], bfr[2];
        #pragma unroll
        for (int t = 0; t < 2; t++) {
            af[t]  = *(const short8*)&As[(wm + t * 16 + l16) * 40 + quad * 8];
            bfr[t] = *(const short8*)&Bs[(wn + t * 16 + l16) * 40 + quad * 8];
        }
        #pragma unroll
        for (int mt = 0; mt < 2; mt++)
            #pragma unroll
            for (int nt = 0; nt < 2; nt++)
                acc[mt][nt] = __builtin_amdgcn_mfma_f32_16x16x32_bf16(
                    af[mt], bfr[nt], acc[mt][nt], 0, 0, 0);
        __syncthreads();
    }
}

// ----------------------------------------------------------- MFMA GEMM -----
template<int AM, int RM, int CM, bool RELU, int SPLIT>
__global__ __launch_bounds__(256)
void gemm_mfma(const void* __restrict__ A, const void* __restrict__ W,
               const void* __restrict__ bias, const void* __restrict__ R,
               void* __restrict__ C, int M, int N, int K,
               const int* __restrict__ flagp)
{
    const bool f32 = (*flagp != 0);
    __shared__ alignas(16) bf16 As[64 * 40];
    __shared__ alignas(16) bf16 Bs[64 * 40];
    const int bm = blockIdx.y << 6, bn = blockIdx.x << 6;
    const int KS = K / SPLIT, z = (SPLIT > 1) ? blockIdx.z : 0;

    f32x4 acc[2][2] = {{{0.f,0.f,0.f,0.f},{0.f,0.f,0.f,0.f}},
                       {{0.f,0.f,0.f,0.f},{0.f,0.f,0.f,0.f}}};
    gemm_core<AM>(A, W, M, K, z * KS, z * KS + KS, bm, bn, f32, As, Bs, acc);

    const int tid = threadIdx.x;
    const int w = tid >> 6, lane = tid & 63;
    const int quad = lane >> 4, l16 = lane & 15;
    const int wm = (w & 1) << 5, wn = (w >> 1) << 5;

    #pragma unroll
    for (int mt = 0; mt < 2; mt++) {
        #pragma unroll
        for (int r = 0; r < 4; r++) {
            const int row = bm + wm + mt * 16 + quad * 4 + r;
            if (row >= M) continue;
            #pragma unroll
            for (int nt = 0; nt < 2; nt++) {
                const int col = bn + wn + nt * 16 + l16;
                if (SPLIT > 1) {
                    ((float*)C)[((size_t)z * M + row) * N + col] = acc[mt][nt][r];
                } else {
                    float v = acc[mt][nt][r] + ldx<2>(bias, col, f32);
                    if (RM >= 0) v += ldx<RM < 0 ? 0 : RM>(R, (size_t)row * N + col, f32);
                    if (RELU) v = fmaxf(v, 0.f);
                    if (CM == 0) ((bf16*)C)[(size_t)row * N + col] = __float2bfloat16(v);
                    else         ((float*)C)[(size_t)row * N + col] = v;
                }
            }
        }
    }
}

// --------------------------------------------------- fused K+V projection --
__global__ __launch_bounds__(256)
void kv_proj(const void* __restrict__ A,
             const void* __restrict__ kw, const void* __restrict__ kb,
             const void* __restrict__ vw, const void* __restrict__ vb,
             bf16* __restrict__ kf, bf16* __restrict__ vf,
             int M, int K, const int* __restrict__ flagp)
{
    const bool f32 = (*flagp != 0);
    __shared__ alignas(16) bf16 As[64 * 40];
    __shared__ alignas(16) bf16 Bs[64 * 40];
    const int sel = blockIdx.x >> 2;
    const void* W  = sel ? vw : kw;
    const void* bs = sel ? vb : kb;
    bf16* C        = sel ? vf : kf;
    const int bn = (blockIdx.x & 3) << 6;
    const int bm = blockIdx.y << 6;

    f32x4 acc[2][2] = {{{0.f,0.f,0.f,0.f},{0.f,0.f,0.f,0.f}},
                       {{0.f,0.f,0.f,0.f},{0.f,0.f,0.f,0.f}}};
    gemm_core<2>(A, W, M, K, 0, K, bm, bn, f32, As, Bs, acc);

    const int tid = threadIdx.x;
    const int w = tid >> 6, lane = tid & 63;
    const int quad = lane >> 4, l16 = lane & 15;
    const int wm = (w & 1) << 5, wn = (w >> 1) << 5;
    #pragma unroll
    for (int mt = 0; mt < 2; mt++)
        #pragma unroll
        for (int r = 0; r < 4; r++) {
            const int row = bm + wm + mt * 16 + quad * 4 + r;
            if (row >= M) continue;
            #pragma unroll
            for (int nt = 0; nt < 2; nt++) {
                const int col = bn + wn + nt * 16 + l16;
                C[(size_t)row * 256 + col] =
                    __float2bfloat16(acc[mt][nt][r] + ldx<2>(bs, col, f32));
            }
        }
}

// -------------------------------------------------------- geometric bias ---
// Transposed output biasT[b][l][q], value = (L2E*beta) * clip(MLP(dist),-10,0)
__global__ __launch_bounds__(256)
void bias_pre(const void* __restrict__ qp, const void* __restrict__ mp,
              const void* __restrict__ w1, const void* __restrict__ b1,
              const void* __restrict__ w2, const void* __restrict__ b2,
              const void* __restrict__ betap, bf16* __restrict__ out,
              const int* __restrict__ flagp)
{
    const bool f32 = (*flagp != 0);
    __shared__ float sw1[KD_], sb1[KD_], sw2[KD_], scst[2];
    const int tid = threadIdx.x;
    if (tid < KD_) {
        sw1[tid] = ldx<2>(w1, tid, f32);
        sb1[tid] = ldx<2>(b1, tid, f32);
        sw2[tid] = ldx<2>(w2, tid, f32);
    }
    if (tid == 0) { scst[0] = ldx<2>(b2, 0, f32); scst[1] = L2E_ * ldx<2>(betap, 0, f32); }
    __syncthreads();
    const int idx = blockIdx.x * 256 + tid;      // 614400 = B*L*75
    const int q8 = idx % 75;
    const int t2 = idx / 75;
    const int l = t2 % L_, b = t2 / L_;
    const int q0 = q8 * 8;
    const float mx = ldx<2>(mp, (size_t)(b * L_ + l) * 3 + 0, f32);
    const float my = ldx<2>(mp, (size_t)(b * L_ + l) * 3 + 1, f32);
    const float mz = ldx<2>(mp, (size_t)(b * L_ + l) * 3 + 2, f32);
    union { short8 s; bf16 h[8]; } res;
    #pragma unroll
    for (int j = 0; j < 8; j++) {
        const int q = q0 + j;
        float dx = ldx<2>(qp, (size_t)(b * Q_ + q) * 3 + 0, f32) - mx;
        float dy = ldx<2>(qp, (size_t)(b * Q_ + q) * 3 + 1, f32) - my;
        float dz = ldx<2>(qp, (size_t)(b * Q_ + q) * 3 + 2, f32) - mz;
        float dist = sqrtf(dx * dx + dy * dy + dz * dz);
        float acc = scst[0];
        #pragma unroll
        for (int k = 0; k < KD_; k++)
            acc += fmaxf(dist * sw1[k] + sb1[k], 0.f) * sw2[k];
        acc = fminf(fmaxf(acc, -10.f), 0.f);
        res.h[j] = __float2bfloat16(scst[1] * acc);
    }
    *(short8*)(out + ((size_t)(b * L_) + l) * Q_ + q0) = res.s;
}

// -------------------------------------------- split-K reduce + res + LN ----
template<int RM, int OM, int S>
__global__ __launch_bounds__(64)
void red_ln(const float* __restrict__ P, const void* __restrict__ bias,
            const void* __restrict__ R, const void* __restrict__ gg,
            const void* __restrict__ bb, void* __restrict__ Y,
            int M, const int* __restrict__ flagp)
{
    const bool f32 = (*flagp != 0);
    const int row = blockIdx.x, lane = threadIdx.x;
    const int d0 = lane * 4;
    float v[4];
    {
        float4 a = *(const float4*)(P + ((size_t)0 * M + row) * D_ + d0);
        v[0] = a.x; v[1] = a.y; v[2] = a.z; v[3] = a.w;
    }
    #pragma unroll
    for (int s = 1; s < S; s++) {
        float4 a = *(const float4*)(P + ((size_t)s * M + row) * D_ + d0);
        v[0] += a.x; v[1] += a.y; v[2] += a.z; v[3] += a.w;
    }
    #pragma unroll
    for (int j = 0; j < 4; j++)
        v[j] += ldx<2>(bias, d0 + j, f32) + ldx<RM>(R, (size_t)row * D_ + d0 + j, f32);

    float s1 = v[0] + v[1] + v[2] + v[3];
    float s2 = v[0]*v[0] + v[1]*v[1] + v[2]*v[2] + v[3]*v[3];
    #pragma unroll
    for (int o = 32; o > 0; o >>= 1) {
        s1 += __shfl_xor(s1, o);
        s2 += __shfl_xor(s2, o);
    }
    const float mean = s1 * (1.f / D_);
    const float var = s2 * (1.f / D_) - mean * mean;
    const float rinv = rsqrtf(var + 1e-5f);
    float o[4];
    #pragma unroll
    for (int j = 0; j < 4; j++)
        o[j] = (v[j] - mean) * rinv * ldx<2>(gg, d0 + j, f32) + ldx<2>(bb, d0 + j, f32);
    const size_t i = (size_t)row * D_ + d0;
    if (OM == 1 || (OM == 2 && f32)) {
        float4 t{o[0], o[1], o[2], o[3]};
        *(float4*)((float*)Y + i) = t;
    } else {
        bf16* y = (bf16*)Y + i;
        y[0] = __float2bfloat16(o[0]); y[1] = __float2bfloat16(o[1]);
        y[2] = __float2bfloat16(o[2]); y[3] = __float2bfloat16(o[3]);
    }
}

// ------------------------------------------------------- flash attention ---
// 1-D grid, XCD-grouped. Bias pre-transposed [b][l][q], L2E*beta folded.
// Static-max softmax (scores provably bounded). Row-sum via ones-row Vt.
// Register-prefetch double-buffer. Psh is wave-private (rows w*16..w*16+15):
// no barrier between exp-write and PV-read.
template<bool HASBIAS, int NSEG>
__global__ __launch_bounds__(256)
void flash_attn(const bf16* __restrict__ Qm, int qs,
                const bf16* __restrict__ Km, int ks,
                const bf16* __restrict__ Vm, int vs,
                const bf16* __restrict__ biasT,       // [b][l][q], pre-scaled
                bf16* __restrict__ pO, float* __restrict__ pml,
                int NQ, int LK)
{
    __shared__ alignas(16) bf16 Ksh[64 * 40];
    __shared__ alignas(16) bf16 Vt[48 * 72];
    __shared__ alignas(16) bf16 Psh[64 * 72];
    __shared__ alignas(16) bf16 Bsh[HASBIAS ? 64 * 72 : 8];

    const int tid = threadIdx.x;
    const int w = tid >> 6, lane = tid & 63;
    const int quad = lane >> 4, l16 = lane & 15;

    const int id = blockIdx.x;
    const int g  = ((id >> 6) << 3) + (id & 7);
    const int h  = (id >> 3) & 7;
    const int qt = g % 10;
    const int zz = g / 10;
    const int b = zz & 3, seg = zz >> 2;
    const int q0 = qt * 64;
    const int segLen = LK / NSEG;
    const int lbeg = seg * segLen, lend = lbeg + segLen;

    // ones/zero rows of Vt (rows 32..47), written once
    for (int i = tid; i < 16 * 72; i += 256) {
        int rr = 32 + i / 72, cc = i % 72;
        Vt[rr * 72 + cc] = __float2bfloat16(rr == 32 ? 1.f : 0.f);
    }

    int qrow = q0 + w * 16 + l16; if (qrow > NQ - 1) qrow = NQ - 1;
    const short8 aq = *(const short8*)(Qm + (size_t)(b * NQ + qrow) * qs + h * HD_ + quad * 8);

    f32x4 O0 = {0.f,0.f,0.f,0.f}, O1 = {0.f,0.f,0.f,0.f}, O2 = {0.f,0.f,0.f,0.f};

    const int srow = tid >> 2, sc4 = tid & 3;
    const int nch = (segLen + 63) >> 6;

    short8 k8, v8, bb8[2];
    auto load_chunk = [&](int l0c) {
        int lg = l0c + srow; if (lg > LK - 1) lg = LK - 1;
        k8 = *(const short8*)(Km + (size_t)(b * LK + lg) * ks + h * HD_ + sc4 * 8);
        v8 = *(const short8*)(Vm + (size_t)(b * LK + lg) * vs + h * HD_ + sc4 * 8);
        if (HASBIAS) {
            #pragma unroll
            for (int rep = 0; rep < 2; rep++) {
                int chid = tid + rep * 256;
                int ll = chid >> 3, qc = chid & 7;
                int qread = q0 + qc * 8;
                if (qread > NQ - 8) qread = NQ - 8;   // clamp; dead cols only
                bb8[rep] = *(const short8*)(biasT + ((size_t)(b * LK) + l0c + ll) * Q_ + qread);
            }
        }
    };
    load_chunk(lbeg);

    for (int ch = 0; ch < nch; ch++) {
        const int l0 = lbeg + (ch << 6);
        // write staged registers -> LDS
        *(short8*)&Ksh[srow * 40 + sc4 * 8] = k8;
        {
            const int swc = srow ^ (sc4 * 16);
            #pragma unroll
            for (int j = 0; j < 8; j++)
                Vt[(sc4 * 8 + j) * 72 + swc] = ((const bf16*)&v8)[j];
        }
        if (HASBIAS) {
            #pragma unroll
            for (int rep = 0; rep < 2; rep++) {
                int chid = tid + rep * 256;
                int ll = chid >> 3, qc = chid & 7;
                *(short8*)&Bsh[ll * 72 + qc * 8] = bb8[rep];
            }
        }
        __syncthreads();
        if (ch + 1 < nch) load_chunk(l0 + 64);   // prefetch next chunk

        f32x4 sv[4];
        #pragma unroll
        for (int jt = 0; jt < 4; jt++) {
            short8 kb = *(const short8*)&Ksh[(jt * 16 + l16) * 40 + quad * 8];
            sv[jt] = __builtin_amdgcn_mfma_f32_16x16x32_bf16(aq, kb, (f32x4){0.f,0.f,0.f,0.f}, 0, 0, 0);
        }
        // static-max softmax: P = exp2(t) directly
        if (l0 + 64 <= lend) {                 // full chunk (always, for cross)
            #pragma unroll
            for (int jt = 0; jt < 4; jt++) {
                if (HASBIAS) {
                    short4v bb = *(const short4v*)&Bsh[(jt * 16 + l16) * 72 + w * 16 + quad * 4];
                    #pragma unroll
                    for (int r = 0; r < 4; r++)
                        Psh[(w * 16 + quad * 4 + r) * 72 + jt * 16 + l16] =
                            __float2bfloat16(exp2f(sv[jt][r] * SL2E_ +
                                __bfloat162float(((const bf16*)&bb)[r])));
                } else {
                    #pragma unroll
                    for (int r = 0; r < 4; r++)
                        Psh[(w * 16 + quad * 4 + r) * 72 + jt * 16 + l16] =
                            __float2bfloat16(exp2f(sv[jt][r] * SL2E_));
                }
            }
        } else {                                // partial tail (self only)
            #pragma unroll
            for (int jt = 0; jt < 4; jt++) {
                const bool valid = (l0 + jt * 16 + l16) < lend;
                #pragma unroll
                for (int r = 0; r < 4; r++)
                    Psh[(w * 16 + quad * 4 + r) * 72 + jt * 16 + l16] =
                        __float2bfloat16(valid ? exp2f(sv[jt][r] * SL2E_) : 0.f);
            }
        }
        // Psh rows are wave-private: no barrier needed before PV reads
        const int sw0 = 16 * (l16 >> 3);
        const int sw1 = 16 * (2 + (l16 >> 3));
        #pragma unroll
        for (int kt = 0; kt < 2; kt++) {
            short8 ap  = *(const short8*)&Psh[(w * 16 + l16) * 72 + kt * 32 + quad * 8];
            short8 bv0 = *(const short8*)&Vt[(l16) * 72 + ((kt * 32 + quad * 8) ^ sw0)];
            short8 bv1 = *(const short8*)&Vt[(16 + l16) * 72 + ((kt * 32 + quad * 8) ^ sw1)];
            short8 bon = *(const short8*)&Vt[(32 + l16) * 72 + kt * 32 + quad * 8];
            O0 = __builtin_amdgcn_mfma_f32_16x16x32_bf16(ap, bv0, O0, 0, 0, 0);
            O1 = __builtin_amdgcn_mfma_f32_16x16x32_bf16(ap, bv1, O1, 0, 0, 0);
            O2 = __builtin_amdgcn_mfma_f32_16x16x32_bf16(ap, bon, O2, 0, 0, 0);
        }
        __syncthreads();
    }

    #pragma unroll
    for (int r = 0; r < 4; r++) {
        const int qg = q0 + w * 16 + quad * 4 + r;
        if (qg >= NQ) continue;
        const float li = __shfl(O2[r], lane & 48);   // col-0 lane of this quad
        const float inv = 1.f / li;
        const size_t rowp = (size_t)(((seg * 4 + b) * 8) + h) * NQ + qg;
        bf16* op = pO + rowp * 32;
        op[l16]      = __float2bfloat16(O0[r] * inv);
        op[16 + l16] = __float2bfloat16(O1[r] * inv);
        if (l16 == 0) { pml[rowp * 2 + 0] = 0.f; pml[rowp * 2 + 1] = O2[r]; }
    }
}

// combine NSEG partials: out = sum_s w_s * Ohat_s, w_s = l_s*2^(m_s-M)/W
template<int NSEG>
__global__ __launch_bounds__(256)
void attn_combine(const bf16* __restrict__ pO, const float* __restrict__ pml,
                  bf16* __restrict__ ctx, int NQ)
{
    const int t = blockIdx.x * 256 + threadIdx.x;
    const int row = t >> 5, d = t & 31;
    const int stride = 32 * NQ;
    float ms[NSEG], ls[NSEG];
    float M = -3e38f;
    #pragma unroll
    for (int s = 0; s < NSEG; s++) {
        ms[s] = pml[(size_t)(s * stride + row) * 2 + 0];
        ls[s] = pml[(size_t)(s * stride + row) * 2 + 1];
        M = fmaxf(M, ms[s]);
    }
    float W = 0.f, acc = 0.f;
    #pragma unroll
    for (int s = 0; s < NSEG; s++) {
        float wgt = ls[s] * exp2f(ms[s] - M);
        W += wgt;
        acc += wgt * __bfloat162float(pO[(size_t)(s * stride + row) * 32 + d]);
    }
    const int bh = row / NQ, q = row - bh * NQ;
    ctx[((size_t)((bh >> 3) * NQ + q)) * D_ + (bh & 7) * HD_ + d] = __float2bfloat16(acc / W);
}

// ---------------------------------------------------------------- launch ---
extern "C" void kernel_launch(void* const* d_in, const int* in_sizes, int n_in,
                              void* d_out, int out_size, void* d_ws, size_t ws_size,
                              hipStream_t stream)
{
    const void* queries   = d_in[0];
    const void* memory    = d_in[1];
    const void* memory_pos= d_in[2];
    const void* query_pos = d_in[3];
    const void* sa_in_w   = d_in[4];
    const void* sa_in_b   = d_in[5];
    const void* sa_out_w  = d_in[6];
    const void* sa_out_b  = d_in[7];
    const void* norm1_g   = d_in[8];
    const void* norm1_b   = d_in[9];
    const void* q_w  = d_in[10], *q_b  = d_in[11];
    const void* k_w  = d_in[12], *k_b  = d_in[13];
    const void* v_w  = d_in[14], *v_b  = d_in[15];
    const void* o_w  = d_in[16], *o_b  = d_in[17];
    const void* norm2_g = d_in[18], *norm2_b = d_in[19];
    const void* beta  = d_in[20];
    const void* dk_w1 = d_in[21], *dk_b1 = d_in[22];
    const void* dk_w2 = d_in[23], *dk_b2 = d_in[24];
    const void* ffn_w1 = d_in[25], *ffn_b1 = d_in[26];
    const void* ffn_w2 = d_in[27], *ffn_b2 = d_in[28];
    const void* norm3_g = d_in[29], *norm3_b = d_in[30];

    // ---- workspace layout (round-17 lifetime-correct), total 30,507,012 B --
    char* base = (char*)d_ws;
    bf16*  kf     = (bf16*)(base + 0);           // 8192x256 bf16 [KV..L9]
    bf16*  vf     = (bf16*)(base + 4194304);     // 8192x256 bf16 [KV..L9]
    bf16*  biasT  = (bf16*)(base + 8388608);     // [b][l][q] bf16 [bias..L9]
    bf16*  qkv    = (bf16*)(base + 18219008);    // 2400x768 bf16 [L1..L2]
    bf16*  sactx  = (bf16*)(base + 18219008);    // 2400x256 bf16 [combS..L3]  (over dead qkv)
    bf16*  selfO  = (bf16*)(base + 21905408);    // 2x19200x32 bf16 [L2..combS]
    float* selfML = (float*)(base + 24363008);   // 2x19200x2 f32  [L2..combS]
    float* P3     = (float*)(base + 21905408);   // 2x2400x256 f32 [L3..R1]    (over dead selfO/ML)
    float* x1     = (float*)(base + 26820608);   // 2400x256 f32   [R1..R2]
    bf16*  qproj  = (bf16*)(base + 29278208);    // 2400x256 bf16  [L5..L9]
    bf16*  crossO = (bf16*)(base + 21905408);    // 4x19200x32 bf16 [L9..combC] (over dead P3)
    float* crossML= (float*)(base + 19447808);   // 4x19200x2 f32  [L9..combC] (over dead qkv)
    bf16*  cactx  = (bf16*)(base + 18219008);    // 2400x256 bf16  [combC..L10] (over dead sactx)
    float* P10    = (float*)(base + 0);          // 2x2400x256 f32 [L10..R2]   (over dead kf)
    float* x2     = (float*)(base + 4915200);    // 2400x256 f32   [R2..R3]    (over dead vf)
    bf16*  ffnh   = (bf16*)(base + 8388608);     // 2400x2048 bf16 [L12..L13]  (over dead biasT)
    float* P13    = (float*)(base + 18219008);   // 4x2400x256 f32 [L13..R3]   (over dead mid)
    int*   flag   = (int*)(base + 30507008);

    const dim3 blk(256);

    detect_kernel<<<1, 256, 0, stream>>>((const unsigned short*)queries, flag);
    // L1. packed QKV projection -> qkv bf16   (separate kernels: the fused
    // input_stage allocated 256 VGPRs for the branch union -> 0.25% occupancy,
    // 281 MB L2 thrash, ~270 us. Keep heterogeneous work in separate kernels.)
    gemm_mfma<2, -1, 0, false, 1><<<dim3(12, 38), blk, 0, stream>>>(
        queries, sa_in_w, sa_in_b, nullptr, qkv, 2400, 768, 256, flag);
    // KV. fused K+V projections -> kf, vf
    kv_proj<<<dim3(8, 128), blk, 0, stream>>>(
        memory, k_w, k_b, v_w, v_b, kf, vf, 8192, 256, flag);
    // L8. geometric bias precompute (transposed, pre-scaled) -> biasT
    bias_pre<<<2400, blk, 0, stream>>>(
        query_pos, memory_pos, dk_w1, dk_b1, dk_w2, dk_b2, beta, biasT, flag);
    // L2. self-attention (1-D XCD-grouped grid, L-split x2) + combine
    flash_attn<false, 2><<<640, blk, 0, stream>>>(
        qkv, 768, qkv + 256, 768, qkv + 512, 768, nullptr,
        selfO, selfML, 600, 600);
    attn_combine<2><<<2400, blk, 0, stream>>>(selfO, selfML, sactx, 600);
    // L3. out-proj, split-K x2 -> P3
    gemm_mfma<0, -1, 1, false, 2><<<dim3(4, 38, 2), blk, 0, stream>>>(
        sactx, sa_out_w, nullptr, nullptr, P3, 2400, 256, 256, flag);
    // R1. reduce + bias + residual(queries) + LN1 -> x1
    red_ln<2, 1, 2><<<2400, 64, 0, stream>>>(
        P3, sa_out_b, queries, norm1_g, norm1_b, x1, 2400, flag);
    // L5. cross Q projection
    gemm_mfma<1, -1, 0, false, 1><<<dim3(4, 38), blk, 0, stream>>>(
        x1, q_w, q_b, nullptr, qproj, 2400, 256, 256, flag);
    // L9. cross-attention (1-D XCD-grouped grid, L-split x4) + combine
    flash_attn<true, 4><<<1280, blk, 0, stream>>>(
        qproj, 256, kf, 256, vf, 256, biasT,
        crossO, crossML, 600, 2048);
    attn_combine<4><<<2400, blk, 0, stream>>>(crossO, crossML, cactx, 600);
    // L10. o-proj, split-K x2 -> P10
    gemm_mfma<0, -1, 1, false, 2><<<dim3(4, 38, 2), blk, 0, stream>>>(
        cactx, o_w, nullptr, nullptr, P10, 2400, 256, 256, flag);
    // R2. reduce + bias + residual(x1) + LN2 -> x2
    red_ln<1, 1, 2><<<2400, 64, 0, stream>>>(
        P10, o_b, x1, norm2_g, norm2_b, x2, 2400, flag);
    // L12. FFN up + ReLU
    gemm_mfma<1, -1, 0, true, 1><<<dim3(32, 38), blk, 0, stream>>>(
        x2, ffn_w1, ffn_b1, nullptr, ffnh, 2400, 2048, 256, flag);
    // L13. FFN down, split-K x4 -> P13
    gemm_mfma<0, -1, 1, false, 4><<<dim3(4, 38, 4), blk, 0, stream>>>(
        ffnh, ffn_w2, nullptr, nullptr, P13, 2400, 256, 2048, flag);
    // R3. reduce + bias + residual(x2) + LN3 -> d_out
    red_ln<1, 2, 4><<<2400, 64, 0, stream>>>(
        P13, ffn_b2, x2, norm3_g, norm3_b, d_out, 2400, flag);
}

// Round 19
// 295.258 us; speedup vs baseline: 1.6827x; 1.0028x over previous
//
#include <hip/hip_runtime.h>
#include <hip/hip_bf16.h>

typedef __hip_bfloat16 bf16;
typedef __attribute__((ext_vector_type(8))) short  short8;   // 8 bf16, 4 VGPRs
typedef __attribute__((ext_vector_type(4))) short  short4v;  // 4 bf16, 2 VGPRs
typedef __attribute__((ext_vector_type(4))) float  f32x4;    // MFMA C/D

#define B_ 4
#define Q_ 600
#define L_ 2048
#define D_ 256
#define H_ 8
#define HD_ 32
#define DFF_ 2048
#define KD_ 32
#define SCALE_ 0.17677669529663687f           // 32^-0.5
#define L2E_   1.4426950408889634f
#define SL2E_  (SCALE_ * L2E_)

// ---- dtype-polymorphic access: MODE 0=bf16, 1=f32, 2=runtime(flag) --------
template<int MODE>
__device__ __forceinline__ float ldx(const void* p, size_t i, bool f32)
{
    if (MODE == 0) return __bfloat162float(((const bf16*)p)[i]);
    if (MODE == 1) return ((const float*)p)[i];
    return f32 ? ((const float*)p)[i] : __bfloat162float(((const bf16*)p)[i]);
}
__device__ __forceinline__ short8 ld8_f32(const float* p)
{
    const float4 a = *(const float4*)p;
    const float4 b = *(const float4*)(p + 4);
    union { short8 s; bf16 h[8]; } u;
    u.h[0] = __float2bfloat16(a.x); u.h[1] = __float2bfloat16(a.y);
    u.h[2] = __float2bfloat16(a.z); u.h[3] = __float2bfloat16(a.w);
    u.h[4] = __float2bfloat16(b.x); u.h[5] = __float2bfloat16(b.y);
    u.h[6] = __float2bfloat16(b.z); u.h[7] = __float2bfloat16(b.w);
    return u.s;
}
template<int MODE>
__device__ __forceinline__ short8 ld8x(const void* p, size_t i, bool f32)
{
    if (MODE == 0) return *(const short8*)((const bf16*)p + i);
    if (MODE == 1) return ld8_f32((const float*)p + i);
    return f32 ? ld8_f32((const float*)p + i) : *(const short8*)((const bf16*)p + i);
}

// ---- A-operand staging: MODE 3 = inline attention-partial combine ---------
// A = bf16 normalized partials [(s*32 + b*8+h)*600+q][32], Al = l weights.
// Produces LN-free softmax-combined row: sum_s l_s*Ohat_s / sum_s l_s.
// Mapping identical to the proven attn_combine kernel.
template<int AM>
__device__ __forceinline__ short8 ld_a(const void* A, const float* Al, int nseg,
                                       int row, int K, int kk, bool f32)
{
    if (AM != 3) return ld8x<AM>(A, (size_t)row * K + kk, f32);
    const int bb = row / 600, qq = row - bb * 600;
    const int h = kk >> 5, d0 = kk & 31;
    float num[8] = {0.f,0.f,0.f,0.f,0.f,0.f,0.f,0.f};
    float den = 0.f;
    for (int s = 0; s < nseg; s++) {
        const size_t rp = (((size_t)(s * 4 + bb) * 8 + h) * 600 + qq);
        const float ls = Al[rp];
        union { short8 s8; bf16 hh[8]; } o;
        o.s8 = *(const short8*)((const bf16*)A + rp * 32 + d0);
        den += ls;
        #pragma unroll
        for (int j = 0; j < 8; j++)
            num[j] += ls * __bfloat162float(o.hh[j]);
    }
    const float inv = 1.f / den;
    union { short8 s8; bf16 hh[8]; } u;
    #pragma unroll
    for (int j = 0; j < 8; j++) u.hh[j] = __float2bfloat16(num[j] * inv);
    return u.s8;
}

// ------------------------------------------------------------ dtype probe --
__global__ __launch_bounds__(256)
void detect_kernel(const unsigned short* __restrict__ q, int* __restrict__ flag)
{
    __shared__ float red[4];
    const int tid = threadIdx.x;
    unsigned short u = q[tid];
    float f = __uint_as_float(((unsigned)(u & 0x7FFF)) << 16);
    if (f != f) f = 1e30f;
    #pragma unroll
    for (int o = 32; o > 0; o >>= 1) f = fmaxf(f, __shfl_xor(f, o));
    if ((tid & 63) == 0) red[tid >> 6] = f;
    __syncthreads();
    if (tid == 0) {
        float m = fmaxf(fmaxf(red[0], red[1]), fmaxf(red[2], red[3]));
        *flag = (m > 100.f) ? 1 : 0;
    }
}

// ------------------------------------------------------- GEMM core (64x64) -
template<int AM>
__device__ __forceinline__ void gemm_core(const void* __restrict__ A,
    const float* __restrict__ Al, int nseg,
    const void* __restrict__ W, int M, int K, int kbeg, int kend,
    int bm, int bn, bool f32, bf16* As, bf16* Bs, f32x4 (&acc)[2][2])
{
    const int tid = threadIdx.x;
    const int w = tid >> 6, lane = tid & 63;
    const int quad = lane >> 4, l16 = lane & 15;
    const int wm = (w & 1) << 5, wn = (w >> 1) << 5;
    const int srow = tid >> 2, scol = (tid & 3) << 3;
    const int gma = (bm + srow < M) ? bm + srow : M - 1;

    short8 pa = ld_a<AM>(A, Al, nseg, gma, K, kbeg + scol, f32);
    short8 pb = ld8x<2>(W, (size_t)(bn + srow) * K + kbeg + scol, f32);

    for (int k0 = kbeg; k0 < kend; k0 += 32) {
        *(short8*)&As[srow * 40 + scol] = pa;
        *(short8*)&Bs[srow * 40 + scol] = pb;
        __syncthreads();
        if (k0 + 32 < kend) {
            pa = ld_a<AM>(A, Al, nseg, gma, K, k0 + 32 + scol, f32);
            pb = ld8x<2>(W, (size_t)(bn + srow) * K + k0 + 32 + scol, f32);
        }
        short8 af[2], bfr[2];
        #pragma unroll
        for (int t = 0; t < 2; t++) {
            af[t]  = *(const short8*)&As[(wm + t * 16 + l16) * 40 + quad * 8];
            bfr[t] = *(const short8*)&Bs[(wn + t * 16 + l16) * 40 + quad * 8];
        }
        #pragma unroll
        for (int mt = 0; mt < 2; mt++)
            #pragma unroll
            for (int nt = 0; nt < 2; nt++)
                acc[mt][nt] = __builtin_amdgcn_mfma_f32_16x16x32_bf16(
                    af[mt], bfr[nt], acc[mt][nt], 0, 0, 0);
        __syncthreads();
    }
}

// ----------------------------------------------------------- MFMA GEMM -----
template<int AM, int RM, int CM, bool RELU, int SPLIT>
__global__ __launch_bounds__(256)
void gemm_mfma(const void* __restrict__ A, const void* __restrict__ W,
               const void* __restrict__ bias, const void* __restrict__ R,
               void* __restrict__ C, int M, int N, int K,
               const float* __restrict__ Al, int nseg,
               const int* __restrict__ flagp)
{
    const bool f32 = (*flagp != 0);
    __shared__ alignas(16) bf16 As[64 * 40];
    __shared__ alignas(16) bf16 Bs[64 * 40];
    const int bm = blockIdx.y << 6, bn = blockIdx.x << 6;
    const int KS = K / SPLIT, z = (SPLIT > 1) ? blockIdx.z : 0;

    f32x4 acc[2][2] = {{{0.f,0.f,0.f,0.f},{0.f,0.f,0.f,0.f}},
                       {{0.f,0.f,0.f,0.f},{0.f,0.f,0.f,0.f}}};
    gemm_core<AM>(A, Al, nseg, W, M, K, z * KS, z * KS + KS, bm, bn, f32, As, Bs, acc);

    const int tid = threadIdx.x;
    const int w = tid >> 6, lane = tid & 63;
    const int quad = lane >> 4, l16 = lane & 15;
    const int wm = (w & 1) << 5, wn = (w >> 1) << 5;

    #pragma unroll
    for (int mt = 0; mt < 2; mt++) {
        #pragma unroll
        for (int r = 0; r < 4; r++) {
            const int row = bm + wm + mt * 16 + quad * 4 + r;
            if (row >= M) continue;
            #pragma unroll
            for (int nt = 0; nt < 2; nt++) {
                const int col = bn + wn + nt * 16 + l16;
                if (SPLIT > 1) {
                    ((float*)C)[((size_t)z * M + row) * N + col] = acc[mt][nt][r];
                } else {
                    float v = acc[mt][nt][r] + ldx<2>(bias, col, f32);
                    if (RM >= 0) v += ldx<RM < 0 ? 0 : RM>(R, (size_t)row * N + col, f32);
                    if (RELU) v = fmaxf(v, 0.f);
                    if (CM == 0) ((bf16*)C)[(size_t)row * N + col] = __float2bfloat16(v);
                    else         ((float*)C)[(size_t)row * N + col] = v;
                }
            }
        }
    }
}

// --------------------------------------------------- fused K+V projection --
__global__ __launch_bounds__(256)
void kv_proj(const void* __restrict__ A,
             const void* __restrict__ kw, const void* __restrict__ kb,
             const void* __restrict__ vw, const void* __restrict__ vb,
             bf16* __restrict__ kf, bf16* __restrict__ vf,
             int M, int K, const int* __restrict__ flagp)
{
    const bool f32 = (*flagp != 0);
    __shared__ alignas(16) bf16 As[64 * 40];
    __shared__ alignas(16) bf16 Bs[64 * 40];
    const int sel = blockIdx.x >> 2;
    const void* W  = sel ? vw : kw;
    const void* bs = sel ? vb : kb;
    bf16* C        = sel ? vf : kf;
    const int bn = (blockIdx.x & 3) << 6;
    const int bm = blockIdx.y << 6;

    f32x4 acc[2][2] = {{{0.f,0.f,0.f,0.f},{0.f,0.f,0.f,0.f}},
                       {{0.f,0.f,0.f,0.f},{0.f,0.f,0.f,0.f}}};
    gemm_core<2>(A, nullptr, 0, W, M, K, 0, K, bm, bn, f32, As, Bs, acc);

    const int tid = threadIdx.x;
    const int w = tid >> 6, lane = tid & 63;
    const int quad = lane >> 4, l16 = lane & 15;
    const int wm = (w & 1) << 5, wn = (w >> 1) << 5;
    #pragma unroll
    for (int mt = 0; mt < 2; mt++)
        #pragma unroll
        for (int r = 0; r < 4; r++) {
            const int row = bm + wm + mt * 16 + quad * 4 + r;
            if (row >= M) continue;
            #pragma unroll
            for (int nt = 0; nt < 2; nt++) {
                const int col = bn + wn + nt * 16 + l16;
                C[(size_t)row * 256 + col] =
                    __float2bfloat16(acc[mt][nt][r] + ldx<2>(bs, col, f32));
            }
        }
}

// -------------------------------------------------------- geometric bias ---
__global__ __launch_bounds__(256)
void bias_pre(const void* __restrict__ qp, const void* __restrict__ mp,
              const void* __restrict__ w1, const void* __restrict__ b1,
              const void* __restrict__ w2, const void* __restrict__ b2,
              const void* __restrict__ betap, bf16* __restrict__ out,
              const int* __restrict__ flagp)
{
    const bool f32 = (*flagp != 0);
    __shared__ float sw1[KD_], sb1[KD_], sw2[KD_], scst[2];
    const int tid = threadIdx.x;
    if (tid < KD_) {
        sw1[tid] = ldx<2>(w1, tid, f32);
        sb1[tid] = ldx<2>(b1, tid, f32);
        sw2[tid] = ldx<2>(w2, tid, f32);
    }
    if (tid == 0) { scst[0] = ldx<2>(b2, 0, f32); scst[1] = L2E_ * ldx<2>(betap, 0, f32); }
    __syncthreads();
    const int idx = blockIdx.x * 256 + tid;      // 614400 = B*L*75
    const int q8 = idx % 75;
    const int t2 = idx / 75;
    const int l = t2 % L_, b = t2 / L_;
    const int q0 = q8 * 8;
    const float mx = ldx<2>(mp, (size_t)(b * L_ + l) * 3 + 0, f32);
    const float my = ldx<2>(mp, (size_t)(b * L_ + l) * 3 + 1, f32);
    const float mz = ldx<2>(mp, (size_t)(b * L_ + l) * 3 + 2, f32);
    union { short8 s; bf16 h[8]; } res;
    #pragma unroll
    for (int j = 0; j < 8; j++) {
        const int q = q0 + j;
        float dx = ldx<2>(qp, (size_t)(b * Q_ + q) * 3 + 0, f32) - mx;
        float dy = ldx<2>(qp, (size_t)(b * Q_ + q) * 3 + 1, f32) - my;
        float dz = ldx<2>(qp, (size_t)(b * Q_ + q) * 3 + 2, f32) - mz;
        float dist = sqrtf(dx * dx + dy * dy + dz * dz);
        float acc = scst[0];
        #pragma unroll
        for (int k = 0; k < KD_; k++)
            acc += fmaxf(dist * sw1[k] + sb1[k], 0.f) * sw2[k];
        acc = fminf(fmaxf(acc, -10.f), 0.f);
        res.h[j] = __float2bfloat16(scst[1] * acc);
    }
    *(short8*)(out + ((size_t)(b * L_) + l) * Q_ + q0) = res.s;
}

// -------------------------------------------- split-K reduce + res + LN ----
template<int RM, int OM, int S>
__global__ __launch_bounds__(64)
void red_ln(const float* __restrict__ P, const void* __restrict__ bias,
            const void* __restrict__ R, const void* __restrict__ gg,
            const void* __restrict__ bb, void* __restrict__ Y,
            int M, const int* __restrict__ flagp)
{
    const bool f32 = (*flagp != 0);
    const int row = blockIdx.x, lane = threadIdx.x;
    const int d0 = lane * 4;
    float v[4];
    {
        float4 a = *(const float4*)(P + ((size_t)0 * M + row) * D_ + d0);
        v[0] = a.x; v[1] = a.y; v[2] = a.z; v[3] = a.w;
    }
    #pragma unroll
    for (int s = 1; s < S; s++) {
        float4 a = *(const float4*)(P + ((size_t)s * M + row) * D_ + d0);
        v[0] += a.x; v[1] += a.y; v[2] += a.z; v[3] += a.w;
    }
    #pragma unroll
    for (int j = 0; j < 4; j++)
        v[j] += ldx<2>(bias, d0 + j, f32) + ldx<RM>(R, (size_t)row * D_ + d0 + j, f32);

    float s1 = v[0] + v[1] + v[2] + v[3];
    float s2 = v[0]*v[0] + v[1]*v[1] + v[2]*v[2] + v[3]*v[3];
    #pragma unroll
    for (int o = 32; o > 0; o >>= 1) {
        s1 += __shfl_xor(s1, o);
        s2 += __shfl_xor(s2, o);
    }
    const float mean = s1 * (1.f / D_);
    const float var = s2 * (1.f / D_) - mean * mean;
    const float rinv = rsqrtf(var + 1e-5f);
    float o[4];
    #pragma unroll
    for (int j = 0; j < 4; j++)
        o[j] = (v[j] - mean) * rinv * ldx<2>(gg, d0 + j, f32) + ldx<2>(bb, d0 + j, f32);
    const size_t i = (size_t)row * D_ + d0;
    if (OM == 1 || (OM == 2 && f32)) {
        float4 t{o[0], o[1], o[2], o[3]};
        *(float4*)((float*)Y + i) = t;
    } else {
        bf16* y = (bf16*)Y + i;
        y[0] = __float2bfloat16(o[0]); y[1] = __float2bfloat16(o[1]);
        y[2] = __float2bfloat16(o[2]); y[3] = __float2bfloat16(o[3]);
    }
}

// ------------------------------------------------------- flash attention ---
// 1-D grid, XCD-grouped. Bias pre-transposed [b][l][q], L2E*beta folded.
// Static-max softmax. Row-sum via ones-row Vt. Register-prefetch dbuf.
// Writes per-seg normalized bf16 partials + l weight; the NEXT gemm's
// A-staging combines them (no separate combine dispatch).
template<bool HASBIAS, int NSEG>
__global__ __launch_bounds__(256)
void flash_attn(const bf16* __restrict__ Qm, int qs,
                const bf16* __restrict__ Km, int ks,
                const bf16* __restrict__ Vm, int vs,
                const bf16* __restrict__ biasT,
                bf16* __restrict__ pO, float* __restrict__ pl,
                int NQ, int LK)
{
    __shared__ alignas(16) bf16 Ksh[64 * 40];
    __shared__ alignas(16) bf16 Vt[48 * 72];
    __shared__ alignas(16) bf16 Psh[64 * 72];
    __shared__ alignas(16) bf16 Bsh[HASBIAS ? 64 * 72 : 8];

    const int tid = threadIdx.x;
    const int w = tid >> 6, lane = tid & 63;
    const int quad = lane >> 4, l16 = lane & 15;

    const int id = blockIdx.x;
    const int g  = ((id >> 6) << 3) + (id & 7);
    const int h  = (id >> 3) & 7;
    const int qt = g % 10;
    const int zz = g / 10;
    const int b = zz & 3, seg = zz >> 2;
    const int q0 = qt * 64;
    const int segLen = LK / NSEG;
    const int lbeg = seg * segLen, lend = lbeg + segLen;

    for (int i = tid; i < 16 * 72; i += 256) {
        int rr = 32 + i / 72, cc = i % 72;
        Vt[rr * 72 + cc] = __float2bfloat16(rr == 32 ? 1.f : 0.f);
    }

    int qrow = q0 + w * 16 + l16; if (qrow > NQ - 1) qrow = NQ - 1;
    const short8 aq = *(const short8*)(Qm + (size_t)(b * NQ + qrow) * qs + h * HD_ + quad * 8);

    f32x4 O0 = {0.f,0.f,0.f,0.f}, O1 = {0.f,0.f,0.f,0.f}, O2 = {0.f,0.f,0.f,0.f};

    const int srow = tid >> 2, sc4 = tid & 3;
    const int nch = (segLen + 63) >> 6;

    short8 k8, v8, bb8[2];
    auto load_chunk = [&](int l0c) {
        int lg = l0c + srow; if (lg > LK - 1) lg = LK - 1;
        k8 = *(const short8*)(Km + (size_t)(b * LK + lg) * ks + h * HD_ + sc4 * 8);
        v8 = *(const short8*)(Vm + (size_t)(b * LK + lg) * vs + h * HD_ + sc4 * 8);
        if (HASBIAS) {
            #pragma unroll
            for (int rep = 0; rep < 2; rep++) {
                int chid = tid + rep * 256;
                int ll = chid >> 3, qc = chid & 7;
                int qread = q0 + qc * 8;
                if (qread > NQ - 8) qread = NQ - 8;
                bb8[rep] = *(const short8*)(biasT + ((size_t)(b * LK) + l0c + ll) * Q_ + qread);
            }
        }
    };
    load_chunk(lbeg);

    for (int ch = 0; ch < nch; ch++) {
        const int l0 = lbeg + (ch << 6);
        *(short8*)&Ksh[srow * 40 + sc4 * 8] = k8;
        {
            const int swc = srow ^ (sc4 * 16);
            #pragma unroll
            for (int j = 0; j < 8; j++)
                Vt[(sc4 * 8 + j) * 72 + swc] = ((const bf16*)&v8)[j];
        }
        if (HASBIAS) {
            #pragma unroll
            for (int rep = 0; rep < 2; rep++) {
                int chid = tid + rep * 256;
                int ll = chid >> 3, qc = chid & 7;
                *(short8*)&Bsh[ll * 72 + qc * 8] = bb8[rep];
            }
        }
        __syncthreads();
        if (ch + 1 < nch) load_chunk(l0 + 64);

        f32x4 sv[4];
        #pragma unroll
        for (int jt = 0; jt < 4; jt++) {
            short8 kb = *(const short8*)&Ksh[(jt * 16 + l16) * 40 + quad * 8];
            sv[jt] = __builtin_amdgcn_mfma_f32_16x16x32_bf16(aq, kb, (f32x4){0.f,0.f,0.f,0.f}, 0, 0, 0);
        }
        if (l0 + 64 <= lend) {
            #pragma unroll
            for (int jt = 0; jt < 4; jt++) {
                if (HASBIAS) {
                    short4v bb = *(const short4v*)&Bsh[(jt * 16 + l16) * 72 + w * 16 + quad * 4];
                    #pragma unroll
                    for (int r = 0; r < 4; r++)
                        Psh[(w * 16 + quad * 4 + r) * 72 + jt * 16 + l16] =
                            __float2bfloat16(exp2f(sv[jt][r] * SL2E_ +
                                __bfloat162float(((const bf16*)&bb)[r])));
                } else {
                    #pragma unroll
                    for (int r = 0; r < 4; r++)
                        Psh[(w * 16 + quad * 4 + r) * 72 + jt * 16 + l16] =
                            __float2bfloat16(exp2f(sv[jt][r] * SL2E_));
                }
            }
        } else {
            #pragma unroll
            for (int jt = 0; jt < 4; jt++) {
                const bool valid = (l0 + jt * 16 + l16) < lend;
                #pragma unroll
                for (int r = 0; r < 4; r++)
                    Psh[(w * 16 + quad * 4 + r) * 72 + jt * 16 + l16] =
                        __float2bfloat16(valid ? exp2f(sv[jt][r] * SL2E_) : 0.f);
            }
        }
        const int sw0 = 16 * (l16 >> 3);
        const int sw1 = 16 * (2 + (l16 >> 3));
        #pragma unroll
        for (int kt = 0; kt < 2; kt++) {
            short8 ap  = *(const short8*)&Psh[(w * 16 + l16) * 72 + kt * 32 + quad * 8];
            short8 bv0 = *(const short8*)&Vt[(l16) * 72 + ((kt * 32 + quad * 8) ^ sw0)];
            short8 bv1 = *(const short8*)&Vt[(16 + l16) * 72 + ((kt * 32 + quad * 8) ^ sw1)];
            short8 bon = *(const short8*)&Vt[(32 + l16) * 72 + kt * 32 + quad * 8];
            O0 = __builtin_amdgcn_mfma_f32_16x16x32_bf16(ap, bv0, O0, 0, 0, 0);
            O1 = __builtin_amdgcn_mfma_f32_16x16x32_bf16(ap, bv1, O1, 0, 0, 0);
            O2 = __builtin_amdgcn_mfma_f32_16x16x32_bf16(ap, bon, O2, 0, 0, 0);
        }
        __syncthreads();
    }

    #pragma unroll
    for (int r = 0; r < 4; r++) {
        const int qg = q0 + w * 16 + quad * 4 + r;
        if (qg >= NQ) continue;
        const float li = __shfl(O2[r], lane & 48);
        const float inv = 1.f / li;
        const size_t rowp = (size_t)(((seg * 4 + b) * 8) + h) * NQ + qg;
        bf16* op = pO + rowp * 32;
        op[l16]      = __float2bfloat16(O0[r] * inv);
        op[16 + l16] = __float2bfloat16(O1[r] * inv);
        if (l16 == 0) pl[rowp] = O2[r];
    }
}

// ---------------------------------------------------------------- launch ---
extern "C" void kernel_launch(void* const* d_in, const int* in_sizes, int n_in,
                              void* d_out, int out_size, void* d_ws, size_t ws_size,
                              hipStream_t stream)
{
    const void* queries   = d_in[0];
    const void* memory    = d_in[1];
    const void* memory_pos= d_in[2];
    const void* query_pos = d_in[3];
    const void* sa_in_w   = d_in[4];
    const void* sa_in_b   = d_in[5];
    const void* sa_out_w  = d_in[6];
    const void* sa_out_b  = d_in[7];
    const void* norm1_g   = d_in[8];
    const void* norm1_b   = d_in[9];
    const void* q_w  = d_in[10], *q_b  = d_in[11];
    const void* k_w  = d_in[12], *k_b  = d_in[13];
    const void* v_w  = d_in[14], *v_b  = d_in[15];
    const void* o_w  = d_in[16], *o_b  = d_in[17];
    const void* norm2_g = d_in[18], *norm2_b = d_in[19];
    const void* beta  = d_in[20];
    const void* dk_w1 = d_in[21], *dk_b1 = d_in[22];
    const void* dk_w2 = d_in[23], *dk_b2 = d_in[24];
    const void* ffn_w1 = d_in[25], *ffn_b1 = d_in[26];
    const void* ffn_w2 = d_in[27], *ffn_b2 = d_in[28];
    const void* norm3_g = d_in[29], *norm3_b = d_in[30];

    // ---- workspace layout, total 31,735,812 B (= round-6 proven size) ----
    char* base = (char*)d_ws;
    bf16*  kf     = (bf16*)(base + 0);           // [KV..L9]
    bf16*  vf     = (bf16*)(base + 4194304);     // [KV..L9]
    bf16*  biasT  = (bf16*)(base + 8388608);     // [bias..L9]  9.83 MB
    bf16*  qkv    = (bf16*)(base + 18219008);    // [L1..L2]    3.69 MB
    float* P3     = (float*)(base + 18219008);   // [L3..R1]  over dead qkv+gap
    bf16*  selfO  = (bf16*)(base + 23134208);    // [L2..L3]  2x19200x32 bf16
    float* selfl  = (float*)(base + 25591808);   // [L2..L3]  2x19200 f32
    float* x1     = (float*)(base + 23134208);   // [R1..R2]  over dead selfO
    bf16*  qproj  = (bf16*)(base + 25591808);    // [L5..L9]  over dead selfl
    bf16*  crossO = (bf16*)(base + 26820608);    // [L9..L10] 4x19200x32 bf16
    float* crossl = (float*)(base + 18219008);   // [L9..L10] over dead P3
    float* P10    = (float*)(base + 0);          // [L10..R2] over dead kf/vf
    float* x2     = (float*)(base + 4915200);    // [R2..R3]  over dead vf
    bf16*  ffnh   = (bf16*)(base + 8388608);     // [L12..L13] over dead biasT
    float* P13    = (float*)(base + 18219008);   // [L13..R3] over dead mid
    int*   flag   = (int*)(base + 31735808);

    const dim3 blk(256);

    detect_kernel<<<1, 256, 0, stream>>>((const unsigned short*)queries, flag);
    // L1. packed QKV projection -> qkv
    gemm_mfma<2, -1, 0, false, 1><<<dim3(12, 38), blk, 0, stream>>>(
        queries, sa_in_w, sa_in_b, nullptr, qkv, 2400, 768, 256, nullptr, 0, flag);
    // KV. fused K+V projections
    kv_proj<<<dim3(8, 128), blk, 0, stream>>>(
        memory, k_w, k_b, v_w, v_b, kf, vf, 8192, 256, flag);
    // L8. geometric bias precompute -> biasT
    bias_pre<<<2400, blk, 0, stream>>>(
        query_pos, memory_pos, dk_w1, dk_b1, dk_w2, dk_b2, beta, biasT, flag);
    // L2. self-attention (L-split x2) -> selfO/selfl partials
    flash_attn<false, 2><<<640, blk, 0, stream>>>(
        qkv, 768, qkv + 256, 768, qkv + 512, 768, nullptr,
        selfO, selfl, 600, 600);
    // L3. out-proj with inline partial-combine staging, split-K x2 -> P3
    gemm_mfma<3, -1, 1, false, 2><<<dim3(4, 38, 2), blk, 0, stream>>>(
        selfO, sa_out_w, nullptr, nullptr, P3, 2400, 256, 256, selfl, 2, flag);
    // R1. reduce + bias + residual(queries) + LN1 -> x1
    red_ln<2, 1, 2><<<2400, 64, 0, stream>>>(
        P3, sa_out_b, queries, norm1_g, norm1_b, x1, 2400, flag);
    // L5. cross Q projection
    gemm_mfma<1, -1, 0, false, 1><<<dim3(4, 38), blk, 0, stream>>>(
        x1, q_w, q_b, nullptr, qproj, 2400, 256, 256, nullptr, 0, flag);
    // L9. cross-attention (L-split x4) -> crossO/crossl partials
    flash_attn<true, 4><<<1280, blk, 0, stream>>>(
        qproj, 256, kf, 256, vf, 256, biasT,
        crossO, crossl, 600, 2048);
    // L10. o-proj with inline partial-combine staging, split-K x2 -> P10
    gemm_mfma<3, -1, 1, false, 2><<<dim3(4, 38, 2), blk, 0, stream>>>(
        crossO, o_w, nullptr, nullptr, P10, 2400, 256, 256, crossl, 4, flag);
    // R2. reduce + bias + residual(x1) + LN2 -> x2
    red_ln<1, 1, 2><<<2400, 64, 0, stream>>>(
        P10, o_b, x1, norm2_g, norm2_b, x2, 2400, flag);
    // L12. FFN up + ReLU
    gemm_mfma<1, -1, 0, true, 1><<<dim3(32, 38), blk, 0, stream>>>(
        x2, ffn_w1, ffn_b1, nullptr, ffnh, 2400, 2048, 256, nullptr, 0, flag);
    // L13. FFN down, split-K x4 -> P13
    gemm_mfma<0, -1, 1, false, 4><<<dim3(4, 38, 4), blk, 0, stream>>>(
        ffnh, ffn_w2, nullptr, nullptr, P13, 2400, 256, 2048, nullptr, 0, flag);
    // R3. reduce + bias + residual(x2) + LN3 -> d_out
    red_ln<1, 2, 4><<<2400, 64, 0, stream>>>(
        P13, ffn_b2, x2, norm3_g, norm3_b, d_out, 2400, flag);
}